// Round 4
// baseline (4310.040 us; speedup 1.0000x reference)
//
#include <hip/hip_runtime.h>
#include <math.h>
#include <stdint.h>

#define NTOK 16384
#define KD   4096
#define EDIM 64
#define MT   32                  // tokens per block
#define KC   128                 // k per chunk
#define NC   (KD / KC)           // 32 chunks
#define BUFF (MT * KC)           // 4096 floats (16 KB) per x buffer
#define LSTR 132                 // logits row stride for epilogue
#define WMAX 261632              // clamp so refill pair (woff, woff+256) stays in-bounds

// token-pair FMA over 8 cols: xs0/xs1 = x scalar for token0/token1; c0,c1 = W cols 0-3,4-7
#define FMA1(xs0, xs1, c0, c1) do { \
    acc0[0]=fmaf(xs0,c0.x,acc0[0]); acc0[1]=fmaf(xs0,c0.y,acc0[1]); \
    acc0[2]=fmaf(xs0,c0.z,acc0[2]); acc0[3]=fmaf(xs0,c0.w,acc0[3]); \
    acc0[4]=fmaf(xs0,c1.x,acc0[4]); acc0[5]=fmaf(xs0,c1.y,acc0[5]); \
    acc0[6]=fmaf(xs0,c1.z,acc0[6]); acc0[7]=fmaf(xs0,c1.w,acc0[7]); \
    acc1[0]=fmaf(xs1,c0.x,acc1[0]); acc1[1]=fmaf(xs1,c0.y,acc1[1]); \
    acc1[2]=fmaf(xs1,c0.z,acc1[2]); acc1[3]=fmaf(xs1,c0.w,acc1[3]); \
    acc1[4]=fmaf(xs1,c1.x,acc1[4]); acc1[5]=fmaf(xs1,c1.y,acc1[5]); \
    acc1[6]=fmaf(xs1,c1.z,acc1[6]); acc1[7]=fmaf(xs1,c1.w,acc1[7]); \
  } while (0)

// consume one 4-k group: xa/xb = 4 k-values (token0/token1); wg = float4 wg[4][2]
// NOTE: parameter must NOT be named 'w' -- it would capture the .w member access in xa.w
#define FMAGRP(xa, xb, wg) do { \
    FMA1(xa.x, xb.x, wg[0][0], wg[0][1]); \
    FMA1(xa.y, xb.y, wg[1][0], wg[1][1]); \
    FMA1(xa.z, xb.z, wg[2][0], wg[2][1]); \
    FMA1(xa.w, xb.w, wg[3][0], wg[3][1]); \
  } while (0)

// load one 4-k x 8-col W group from (p)
#define WLOAD(wg, p) do { \
    wg[0][0] = *(const float4*)((p));       wg[0][1] = *(const float4*)((p) + 4);   \
    wg[1][0] = *(const float4*)((p) + 64);  wg[1][1] = *(const float4*)((p) + 68);  \
    wg[2][0] = *(const float4*)((p) + 128); wg[2][1] = *(const float4*)((p) + 132); \
    wg[3][0] = *(const float4*)((p) + 192); wg[3][1] = *(const float4*)((p) + 196); \
  } while (0)

#define LD4(p) (*(const float4*)(p))

#define XSTAGE(dbase) do { \
    float* d_ = (dbase) + srow * KC; \
    *(float4*)&d_[((sc0 + 0) ^ ssw) << 2] = s0; \
    *(float4*)&d_[((sc0 + 1) ^ ssw) << 2] = s1; \
    *(float4*)&d_[((sc0 + 2) ^ ssw) << 2] = s2; \
    *(float4*)&d_[((sc0 + 3) ^ ssw) << 2] = s3; \
  } while (0)

__global__ __launch_bounds__(256, 2)
void router_fused(const float* __restrict__ x,
                  const float* __restrict__ noise,
                  const float* __restrict__ Wr,
                  const float* __restrict__ br,
                  const float* __restrict__ Wn,
                  const float* __restrict__ bn,
                  float* __restrict__ out) {
    __shared__ float smem[2 * BUFF];        // 32 KB; logits area reuses it at the end
    const int tid  = threadIdx.x;
    const int t0   = blockIdx.x * MT;
    const int lane = tid & 63;
    const int wv   = tid >> 6;              // wave 0..3
    const int tg   = lane >> 2;             // 0..15 -> tokens 2tg, 2tg+1
    const int cg   = lane & 3;              // 8-col group within wave
    const int r0   = 2 * tg;
    const int r1   = r0 + 1;
    const int sw   = tg & 7;                // x read swizzle key = (row>>1)&7

    // wave -> 32 cols: wv 0,1 -> Wr cols 0..63 ; wv 2,3 -> Wn cols 0..63
    const float* __restrict__ wcol = ((wv < 2) ? Wr : Wn) + ((wv & 1) * 32 + cg * 8);

    // staging: thread -> token row srow, 16 consecutive k; swizzled 16B-chunk writes
    const int srow = tid >> 3;              // 0..31
    const int skq  = (tid & 7) * 16;
    const int sc0  = skq >> 2;
    const int ssw  = (srow >> 1) & 7;       // must match read key
    const float* xsrc = x + (size_t)(t0 + srow) * KD + skq;

    float acc0[8], acc1[8];
#pragma unroll
    for (int j = 0; j < 8; ++j) { acc0[j] = 0.f; acc1[j] = 0.f; }

    // ---- prologue: stage x chunk 0 ----
    float4 s0, s1, s2, s3;
    s0 = LD4(xsrc); s1 = LD4(xsrc + 4); s2 = LD4(xsrc + 8); s3 = LD4(xsrc + 12);
    XSTAGE(smem);

    // ---- W 4-deep register ring: preload groups 0..3 ----
    float4 wA[4][2], wB[4][2], wC[4][2], wD[4][2];
    WLOAD(wA, wcol);
    WLOAD(wB, wcol + 256);
    WLOAD(wC, wcol + 512);
    WLOAD(wD, wcol + 768);
    int woff = 1024;                        // next refill = group 4 (floats)

    for (int c = 0; c < NC; ++c) {
        __syncthreads();                    // x buf[c&1] ready
        const bool pre = (c + 1) < NC;
        if (pre) {                          // issue next x chunk global loads early
            const float* xs = xsrc + (size_t)(c + 1) * KC;
            s0 = LD4(xs); s1 = LD4(xs + 4); s2 = LD4(xs + 8); s3 = LD4(xs + 12);
        }

        const char* xrb = (const char*)(smem + (c & 1) * BUFF + r0 * KC);

        // body-0 x regs (groups 0,1): only cold LDS read per chunk
        float4 xc0, xc1, xc2, xc3;
        {
            const int oa = (0 ^ sw) << 4, ob = (1 ^ sw) << 4;
            xc0 = LD4(xrb + oa); xc1 = LD4(xrb + oa + 512);
            xc2 = LD4(xrb + ob); xc3 = LD4(xrb + ob + 512);
        }

#pragma unroll 2
        for (int bb = 0; bb < 8; ++bb) {
            const int g0 = 4 * bb;
            // x for odd body (groups g0+2, g0+3) -- full-body issue-to-use distance
            float4 xn0, xn1, xn2, xn3;
            {
                const int oa = ((g0 + 2) ^ sw) << 4, ob = ((g0 + 3) ^ sw) << 4;
                xn0 = LD4(xrb + oa); xn1 = LD4(xrb + oa + 512);
                xn2 = LD4(xrb + ob); xn3 = LD4(xrb + ob + 512);
            }
            // even body: consume groups g0, g0+1; refill A,B (used 2 bodies later)
            FMAGRP(xc0, xc1, wA);
            FMAGRP(xc2, xc3, wB);
            WLOAD(wA, wcol + woff);
            WLOAD(wB, wcol + woff + 256);
            woff = (woff + 512 > WMAX) ? WMAX : woff + 512;
            // x for next even body (groups g0+4, g0+5)
            if (bb < 7) {
                const int oa = ((g0 + 4) ^ sw) << 4, ob = ((g0 + 5) ^ sw) << 4;
                xc0 = LD4(xrb + oa); xc1 = LD4(xrb + oa + 512);
                xc2 = LD4(xrb + ob); xc3 = LD4(xrb + ob + 512);
            }
            // odd body: consume groups g0+2, g0+3; refill C,D
            FMAGRP(xn0, xn1, wC);
            FMAGRP(xn2, xn3, wD);
            WLOAD(wC, wcol + woff);
            WLOAD(wD, wcol + woff + 256);
            woff = (woff + 512 > WMAX) ? WMAX : woff + 512;
        }

        if (pre) XSTAGE(smem + ((c + 1) & 1) * BUFF);   // write staged x to other buffer
    }

    // ---- logits -> LDS [32 tokens][132]: cols 0..63 route, 64..127 noise ----
    __syncthreads();   // all waves done reading x buffers (logits area overlaps them)
    {
        const int colbase = wv * 32 + cg * 8;
        *(float4*)&smem[r0 * LSTR + colbase]     = make_float4(acc0[0], acc0[1], acc0[2], acc0[3]);
        *(float4*)&smem[r0 * LSTR + colbase + 4] = make_float4(acc0[4], acc0[5], acc0[6], acc0[7]);
        *(float4*)&smem[r1 * LSTR + colbase]     = make_float4(acc1[0], acc1[1], acc1[2], acc1[3]);
        *(float4*)&smem[r1 * LSTR + colbase + 4] = make_float4(acc1[4], acc1[5], acc1[6], acc1[7]);
    }
    __syncthreads();

    // ---- epilogue: wave per token, lane = expert (numerics unchanged) ----
    const float brl = br[lane], bnl = bn[lane];
    for (int it = 0; it < 8; ++it) {
        const int tl  = wv * 8 + it;
        const int tg_ = t0 + tl;
        float v  = smem[tl * LSTR + lane] + brl;
        float nz = smem[tl * LSTR + 64 + lane] + bnl;
        float sp = log1pf(expf(-fabsf(nz))) + fmaxf(nz, 0.f);   // stable softplus
        v += noise[(size_t)tg_ * EDIM + lane] * sp;

        float mx = v;
#pragma unroll
        for (int o = 32; o >= 1; o >>= 1) mx = fmaxf(mx, __shfl_xor(mx, o, 64));
        float p = expf(v - mx);
        float sm = p;
#pragma unroll
        for (int o = 32; o >= 1; o >>= 1) sm += __shfl_xor(sm, o, 64);
        float prob = p / sm;
        out[(size_t)NTOK * 16 + (size_t)tg_ * EDIM + lane] = prob;   // output 2

        float pv = prob;
        float wvals[8]; int widx[8]; float tsum = 0.f;
#pragma unroll
        for (int j = 0; j < 8; ++j) {
            float bv = pv; int bi = lane;
#pragma unroll
            for (int o = 32; o >= 1; o >>= 1) {
                float ov = __shfl_xor(bv, o, 64);
                int   oi = __shfl_xor(bi, o, 64);
                if (ov > bv || (ov == bv && oi < bi)) { bv = ov; bi = oi; }
            }
            wvals[j] = bv; widx[j] = bi; tsum += bv;
            if (lane == bi) pv = -1.0f;
        }
        if (lane < 8) {
            float myw = wvals[0]; int myi = widx[0];
#pragma unroll
            for (int j = 1; j < 8; ++j) if (lane == j) { myw = wvals[j]; myi = widx[j]; }
            out[(size_t)tg_ * 8 + lane] = myw / tsum;                       // output 0
            out[(size_t)NTOK * 8 + (size_t)tg_ * 8 + lane] = (float)myi;    // output 1
        }
    }
}

extern "C" void kernel_launch(void* const* d_in, const int* in_sizes, int n_in,
                              void* d_out, int out_size, void* d_ws, size_t ws_size,
                              hipStream_t stream) {
    const float* x     = (const float*)d_in[0];
    const float* noise = (const float*)d_in[1];
    const float* Wr    = (const float*)d_in[2];
    const float* br    = (const float*)d_in[3];
    const float* Wn    = (const float*)d_in[4];
    const float* bn    = (const float*)d_in[5];
    float* out = (float*)d_out;
    hipLaunchKernelGGL(router_fused, dim3(NTOK / MT), dim3(256), 0, stream,
                       x, noise, Wr, br, Wn, bn, out);
}

// Round 6
// 909.311 us; speedup vs baseline: 4.7399x; 4.7399x over previous
//
#include <hip/hip_runtime.h>
#include <math.h>
#include <stdint.h>

#define NTOK 16384
#define KD   4096
#define EDIM 64
#define MT   32                  // tokens per block
#define KC   128                 // k per chunk
#define NC   (KD / KC)           // 32 chunks
#define BUFF (MT * KC)           // 4096 floats (16 KB) per x buffer
#define LSTR 132                 // logits row stride for epilogue
#define WMAX 261888              // last group offset (group 1023 * 256 floats)

// token-pair FMA over 8 cols: xs0/xs1 = x scalar for token0/token1; c0,c1 = W cols 0-3,4-7
#define FMA1(xs0, xs1, c0, c1) do { \
    acc0[0]=fmaf(xs0,c0.x,acc0[0]); acc0[1]=fmaf(xs0,c0.y,acc0[1]); \
    acc0[2]=fmaf(xs0,c0.z,acc0[2]); acc0[3]=fmaf(xs0,c0.w,acc0[3]); \
    acc0[4]=fmaf(xs0,c1.x,acc0[4]); acc0[5]=fmaf(xs0,c1.y,acc0[5]); \
    acc0[6]=fmaf(xs0,c1.z,acc0[6]); acc0[7]=fmaf(xs0,c1.w,acc0[7]); \
    acc1[0]=fmaf(xs1,c0.x,acc1[0]); acc1[1]=fmaf(xs1,c0.y,acc1[1]); \
    acc1[2]=fmaf(xs1,c0.z,acc1[2]); acc1[3]=fmaf(xs1,c0.w,acc1[3]); \
    acc1[4]=fmaf(xs1,c1.x,acc1[4]); acc1[5]=fmaf(xs1,c1.y,acc1[5]); \
    acc1[6]=fmaf(xs1,c1.z,acc1[6]); acc1[7]=fmaf(xs1,c1.w,acc1[7]); \
  } while (0)

// consume one 4-k group: xa/xb = 4 k-values (token0/token1); wg = float4 wg[4][2]
// NOTE: parameter must NOT be named 'w' (would capture the .w member access in xa.w)
#define FMAGRP(xa, xb, wg) do { \
    FMA1(xa.x, xb.x, wg[0][0], wg[0][1]); \
    FMA1(xa.y, xb.y, wg[1][0], wg[1][1]); \
    FMA1(xa.z, xb.z, wg[2][0], wg[2][1]); \
    FMA1(xa.w, xb.w, wg[3][0], wg[3][1]); \
  } while (0)

// load one 4-k x 8-col W group from (p)
#define WLOAD(wg, p) do { \
    wg[0][0] = *(const float4*)((p));       wg[0][1] = *(const float4*)((p) + 4);   \
    wg[1][0] = *(const float4*)((p) + 64);  wg[1][1] = *(const float4*)((p) + 68);  \
    wg[2][0] = *(const float4*)((p) + 128); wg[2][1] = *(const float4*)((p) + 132); \
    wg[3][0] = *(const float4*)((p) + 192); wg[3][1] = *(const float4*)((p) + 196); \
  } while (0)

#define LD4(p) (*(const float4*)(p))

#define XSTAGE(dbase) do { \
    float* d_ = (dbase) + srow * KC; \
    *(float4*)&d_[((sc0 + 0) ^ ssw) << 2] = s0; \
    *(float4*)&d_[((sc0 + 1) ^ ssw) << 2] = s1; \
    *(float4*)&d_[((sc0 + 2) ^ ssw) << 2] = s2; \
    *(float4*)&d_[((sc0 + 3) ^ ssw) << 2] = s3; \
  } while (0)

__global__ __launch_bounds__(256)
void router_fused(const float* __restrict__ x,
                  const float* __restrict__ noise,
                  const float* __restrict__ Wr,
                  const float* __restrict__ br,
                  const float* __restrict__ Wn,
                  const float* __restrict__ bn,
                  float* __restrict__ out) {
    __shared__ float smem[2 * BUFF];        // 32 KB; logits area reuses it at the end
    const int tid  = threadIdx.x;
    const int t0   = blockIdx.x * MT;
    const int lane = tid & 63;
    const int wv   = tid >> 6;              // wave 0..3
    const int tg   = lane >> 2;             // 0..15 -> tokens 2tg, 2tg+1
    const int cg   = lane & 3;              // 8-col group within wave
    const int r0   = 2 * tg;
    const int r1   = r0 + 1;
    const int sw   = tg & 7;                // x read swizzle key = (row>>1)&7

    // wave -> 32 cols: wv 0,1 -> Wr cols 0..63 ; wv 2,3 -> Wn cols 0..63
    const float* __restrict__ wcol = ((wv < 2) ? Wr : Wn) + ((wv & 1) * 32 + cg * 8);

    // staging: thread -> token row srow, 16 consecutive k; swizzled 16B-chunk writes
    const int srow = tid >> 3;              // 0..31
    const int skq  = (tid & 7) * 16;
    const int sc0  = skq >> 2;              // 16B-chunk index base
    const int ssw  = (srow >> 1) & 7;       // must match read key
    const float* xsrc = x + (size_t)(t0 + srow) * KD + skq;

    float acc0[8], acc1[8];
#pragma unroll
    for (int j = 0; j < 8; ++j) { acc0[j] = 0.f; acc1[j] = 0.f; }

    // ---- prologue: stage x chunk 0 ----
    float4 s0, s1, s2, s3;
    s0 = LD4(xsrc); s1 = LD4(xsrc + 4); s2 = LD4(xsrc + 8); s3 = LD4(xsrc + 12);
    XSTAGE(smem);

    // ---- W 2-deep register ring: preload groups 0,1 ----
    float4 wA[4][2], wB[4][2];
    WLOAD(wA, wcol);
    WLOAD(wB, wcol + 256);
    int woff = 512;                         // next refill = group 2 (float offset)

    for (int c = 0; c < NC; ++c) {
        __syncthreads();                    // x buf[c&1] ready
        const bool pre = (c + 1) < NC;
        if (pre) {                          // issue next x chunk global loads early
            const float* xs = xsrc + (size_t)(c + 1) * KC;
            s0 = LD4(xs); s1 = LD4(xs + 4); s2 = LD4(xs + 8); s3 = LD4(xs + 12);
        }

        const char* xrb = (const char*)(smem + (c & 1) * BUFF + r0 * KC);

        // cold x read: groups 0,1 of this chunk (both tokens)
        float4 xc0, xc1, xc2, xc3;
        {
            const int oa = (0 ^ sw) << 4, ob = (1 ^ sw) << 4;
            xc0 = LD4(xrb + oa); xc1 = LD4(xrb + oa + 512);
            xc2 = LD4(xrb + ob); xc3 = LD4(xrb + ob + 512);
        }

#pragma unroll 2
        for (int gp = 0; gp < 16; ++gp) {   // 2 groups (8 k) per iteration
            const int g = 2 * gp;
            // x for next iteration (groups g+2, g+3): full-iteration issue-to-use distance
            float4 xn0, xn1, xn2, xn3;
            if (gp < 15) {
                const int oa = ((g + 2) ^ sw) << 4, ob = ((g + 3) ^ sw) << 4;
                xn0 = LD4(xrb + oa); xn1 = LD4(xrb + oa + 512);
                xn2 = LD4(xrb + ob); xn3 = LD4(xrb + ob + 512);
            }
            // consume group g with wA, refill wA <- group g+2 (used next iteration)
            FMAGRP(xc0, xc1, wA);
            WLOAD(wA, wcol + woff);
            woff = (woff + 256 > WMAX) ? WMAX : woff + 256;
            // consume group g+1 with wB, refill wB <- group g+3
            FMAGRP(xc2, xc3, wB);
            WLOAD(wB, wcol + woff);
            woff = (woff + 256 > WMAX) ? WMAX : woff + 256;
            if (gp < 15) { xc0 = xn0; xc1 = xn1; xc2 = xn2; xc3 = xn3; }
        }

        if (pre) XSTAGE(smem + ((c + 1) & 1) * BUFF);   // write staged x to other buffer
    }

    // ---- logits -> LDS [32 tokens][132]: cols 0..63 route, 64..127 noise ----
    __syncthreads();   // all waves done reading x buffers (logits area overlaps them)
    {
        const int colbase = wv * 32 + cg * 8;
        *(float4*)&smem[r0 * LSTR + colbase]     = make_float4(acc0[0], acc0[1], acc0[2], acc0[3]);
        *(float4*)&smem[r0 * LSTR + colbase + 4] = make_float4(acc0[4], acc0[5], acc0[6], acc0[7]);
        *(float4*)&smem[r1 * LSTR + colbase]     = make_float4(acc1[0], acc1[1], acc1[2], acc1[3]);
        *(float4*)&smem[r1 * LSTR + colbase + 4] = make_float4(acc1[4], acc1[5], acc1[6], acc1[7]);
    }
    __syncthreads();

    // ---- epilogue: wave per token, lane = expert (numerics unchanged) ----
    const float brl = br[lane], bnl = bn[lane];
    for (int it = 0; it < 8; ++it) {
        const int tl  = wv * 8 + it;
        const int tg_ = t0 + tl;
        float v  = smem[tl * LSTR + lane] + brl;
        float nz = smem[tl * LSTR + 64 + lane] + bnl;
        float sp = log1pf(expf(-fabsf(nz))) + fmaxf(nz, 0.f);   // stable softplus
        v += noise[(size_t)tg_ * EDIM + lane] * sp;

        float mx = v;
#pragma unroll
        for (int o = 32; o >= 1; o >>= 1) mx = fmaxf(mx, __shfl_xor(mx, o, 64));
        float p = expf(v - mx);
        float sm = p;
#pragma unroll
        for (int o = 32; o >= 1; o >>= 1) sm += __shfl_xor(sm, o, 64);
        float prob = p / sm;
        out[(size_t)NTOK * 16 + (size_t)tg_ * EDIM + lane] = prob;   // output 2

        float pv = prob;
        float wvals[8]; int widx[8]; float tsum = 0.f;
#pragma unroll
        for (int j = 0; j < 8; ++j) {
            float bv = pv; int bi = lane;
#pragma unroll
            for (int o = 32; o >= 1; o >>= 1) {
                float ov = __shfl_xor(bv, o, 64);
                int   oi = __shfl_xor(bi, o, 64);
                if (ov > bv || (ov == bv && oi < bi)) { bv = ov; bi = oi; }
            }
            wvals[j] = bv; widx[j] = bi; tsum += bv;
            if (lane == bi) pv = -1.0f;
        }
        if (lane < 8) {
            float myw = wvals[0]; int myi = widx[0];
#pragma unroll
            for (int j = 1; j < 8; ++j) if (lane == j) { myw = wvals[j]; myi = widx[j]; }
            out[(size_t)tg_ * 8 + lane] = myw / tsum;                       // output 0
            out[(size_t)NTOK * 8 + (size_t)tg_ * 8 + lane] = (float)myi;    // output 1
        }
    }
}

extern "C" void kernel_launch(void* const* d_in, const int* in_sizes, int n_in,
                              void* d_out, int out_size, void* d_ws, size_t ws_size,
                              hipStream_t stream) {
    const float* x     = (const float*)d_in[0];
    const float* noise = (const float*)d_in[1];
    const float* Wr    = (const float*)d_in[2];
    const float* br    = (const float*)d_in[3];
    const float* Wn    = (const float*)d_in[4];
    const float* bn    = (const float*)d_in[5];
    float* out = (float*)d_out;
    hipLaunchKernelGGL(router_fused, dim3(NTOK / MT), dim3(256), 0, stream,
                       x, noise, Wr, br, Wn, bn, out);
}

// Round 7
// 557.397 us; speedup vs baseline: 7.7324x; 1.6314x over previous
//
#include <hip/hip_runtime.h>
#include <math.h>
#include <stdint.h>

#define NTOK 16384
#define KD   4096
#define EDIM 64
#define MT   64                 // tokens per block
#define KQ   1024               // k per quarter (split-K4)
#define KC   16                 // k per chunk-step
#define NS   (KQ / KC)          // 64 steps
#define QSTR 3072               // floats per quarter region: x 16x64 + W 16x128
#define BSTR (4 * QSTR)         // 12288 floats per buffer
#define PSTR 132                // logits row stride
#define PQ   (MT * PSTR)        // 8448 floats per partial region
#define SMEMF (4 * PQ)          // 33792 floats = 132 KB (>= 2*BSTR = 24576)

#define LD4(p) (*(const float4*)(p))

// one k-slice: xs scalar (token i) times 8 W cols (wa, wb)
#define FMAK(xs, i) do { \
    acc[i][0] = fmaf(xs, wa.x, acc[i][0]); \
    acc[i][1] = fmaf(xs, wa.y, acc[i][1]); \
    acc[i][2] = fmaf(xs, wa.z, acc[i][2]); \
    acc[i][3] = fmaf(xs, wa.w, acc[i][3]); \
    acc[i][4] = fmaf(xs, wb.x, acc[i][4]); \
    acc[i][5] = fmaf(xs, wb.y, acc[i][5]); \
    acc[i][6] = fmaf(xs, wb.z, acc[i][6]); \
    acc[i][7] = fmaf(xs, wb.w, acc[i][7]); \
  } while (0)

__global__ __launch_bounds__(512, 2)
void router_fused(const float* __restrict__ x,
                  const float* __restrict__ noise,
                  const float* __restrict__ Wr,
                  const float* __restrict__ br,
                  const float* __restrict__ Wn,
                  const float* __restrict__ bn,
                  float* __restrict__ out) {
    __shared__ float smem[SMEMF];
    const int tid  = threadIdx.x;
    const int t0   = blockIdx.x * MT;
    const int lane = tid & 63;
    const int wv   = tid >> 6;          // 0..7
    const int q    = wv >> 1;           // k-quarter 0..3
    const int m    = wv & 1;            // 0 = route cols, 1 = noise cols
    const int tg   = lane >> 3;         // token group: tokens 8tg..8tg+7
    const int cg   = lane & 7;          // col group: cols m*64 + 8cg .. +7
    const int colb = m * 64 + cg * 8;   // combined col base (0..127)

    // ---- staging roles (all 512 threads stage all 4 quarters) ----
    const int sq    = tid >> 7;         // quarter staged by this thread
    const int st    = tid & 127;
    const int stok  = st >> 1;          // 0..63 token
    const int skc   = (st & 1) * 8;     // k offset 0 or 8 (8 consecutive k)
    const int skrow = st >> 3;          // 0..15 W k-row
    const int sseg  = st & 7;           // 16-col segment 0..7
    const float* xsrc = x + (size_t)(t0 + stok) * KD + sq * KQ + skc;
    const float* wsrc = (sseg < 4) ? (Wr + sseg * 16) : (Wn + (sseg - 4) * 16);
    wsrc += (size_t)(sq * KQ + skrow) * EDIM;
    const int wkey = (skrow & 7) << 2;  // XOR swizzle key (floats) for W rows

    float acc[8][8];
#pragma unroll
    for (int i = 0; i < 8; ++i)
#pragma unroll
        for (int j = 0; j < 8; ++j) acc[i][j] = 0.f;

    float4 gx0, gx1, gw0, gw1, gw2, gw3;

#define GLOAD(s) do { \
        const float* xp = xsrc + (s) * KC; \
        gx0 = LD4(xp); gx1 = LD4(xp + 4); \
        const float* wp = wsrc + (size_t)(s) * KC * EDIM; \
        gw0 = LD4(wp); gw1 = LD4(wp + 4); gw2 = LD4(wp + 8); gw3 = LD4(wp + 12); \
    } while (0)

#define XWRITE(b) do { \
        float* xb_ = smem + (b) * BSTR + sq * QSTR; \
        xb_[(skc + 0) * 64 + stok] = gx0.x; \
        xb_[(skc + 1) * 64 + stok] = gx0.y; \
        xb_[(skc + 2) * 64 + stok] = gx0.z; \
        xb_[(skc + 3) * 64 + stok] = gx0.w; \
        xb_[(skc + 4) * 64 + stok] = gx1.x; \
        xb_[(skc + 5) * 64 + stok] = gx1.y; \
        xb_[(skc + 6) * 64 + stok] = gx1.z; \
        xb_[(skc + 7) * 64 + stok] = gx1.w; \
        float* wb_ = xb_ + 1024; \
        const int c0_ = sseg * 16; \
        *(float4*)&wb_[skrow * 128 + ((c0_ +  0) ^ wkey)] = gw0; \
        *(float4*)&wb_[skrow * 128 + ((c0_ +  4) ^ wkey)] = gw1; \
        *(float4*)&wb_[skrow * 128 + ((c0_ +  8) ^ wkey)] = gw2; \
        *(float4*)&wb_[skrow * 128 + ((c0_ + 12) ^ wkey)] = gw3; \
    } while (0)

    // ---- prologue ----
    GLOAD(0);
    XWRITE(0);

    for (int s = 0; s < NS; ++s) {
        __syncthreads();                    // buffer s&1 ready
        if (s + 1 < NS) GLOAD(s + 1);       // issue next-step global loads early

        const float* xq = smem + (s & 1) * BSTR + q * QSTR;
        const float* wq = xq + 1024;

#pragma unroll 4
        for (int kk = 0; kk < KC; ++kk) {
            float4 xa = LD4(&xq[kk * 64 + tg * 8]);       // tokens 8tg..+3 (8-distinct, cg-broadcast)
            float4 xc = LD4(&xq[kk * 64 + tg * 8 + 4]);   // tokens 8tg+4..+7
            const int key = (kk & 7) << 2;
            float4 wa = LD4(&wq[kk * 128 + ((colb)     ^ key)]);  // cols colb..+3
            float4 wb = LD4(&wq[kk * 128 + ((colb + 4) ^ key)]);  // cols colb+4..+7
            FMAK(xa.x, 0); FMAK(xa.y, 1); FMAK(xa.z, 2); FMAK(xa.w, 3);
            FMAK(xc.x, 4); FMAK(xc.y, 5); FMAK(xc.z, 6); FMAK(xc.w, 7);
        }

        __syncthreads();                    // compute done; safe to overwrite other buffer
        if (s + 1 < NS) XWRITE((s + 1) & 1);
    }

    // ---- partial sums -> LDS part[q][64][132] ----
    __syncthreads();
    {
        float* pq_ = smem + q * PQ;
#pragma unroll
        for (int i = 0; i < 8; ++i) {
            *(float4*)&pq_[(tg * 8 + i) * PSTR + colb] =
                make_float4(acc[i][0], acc[i][1], acc[i][2], acc[i][3]);
            *(float4*)&pq_[(tg * 8 + i) * PSTR + colb + 4] =
                make_float4(acc[i][4], acc[i][5], acc[i][6], acc[i][7]);
        }
    }
    __syncthreads();

    // ---- combine 4 k-quarters into part[0] ----
#pragma unroll
    for (int j = 0; j < 16; ++j) {
        const int idx = tid + 512 * j;          // 0..8191
        const int tok = idx >> 7, col = idx & 127;
        const int li  = tok * PSTR + col;
        smem[li] = (smem[li] + smem[PQ + li]) + (smem[2 * PQ + li] + smem[3 * PQ + li]);
    }
    __syncthreads();

    // ---- epilogue: wave per token, lane = expert (numerics unchanged) ----
    const float brl = br[lane], bnl = bn[lane];
    for (int it = 0; it < 8; ++it) {
        const int tl  = wv * 8 + it;            // 0..63
        const int tg_ = t0 + tl;
        float v  = smem[tl * PSTR + lane] + brl;
        float nz = smem[tl * PSTR + 64 + lane] + bnl;
        float sp = log1pf(expf(-fabsf(nz))) + fmaxf(nz, 0.f);   // stable softplus
        v += noise[(size_t)tg_ * EDIM + lane] * sp;

        float mx = v;
#pragma unroll
        for (int o = 32; o >= 1; o >>= 1) mx = fmaxf(mx, __shfl_xor(mx, o, 64));
        float p = expf(v - mx);
        float sm = p;
#pragma unroll
        for (int o = 32; o >= 1; o >>= 1) sm += __shfl_xor(sm, o, 64);
        float prob = p / sm;
        out[(size_t)NTOK * 16 + (size_t)tg_ * EDIM + lane] = prob;   // output 2

        float pv = prob;
        float wvals[8]; int widx[8]; float tsum = 0.f;
#pragma unroll
        for (int j = 0; j < 8; ++j) {
            float bv = pv; int bi = lane;
#pragma unroll
            for (int o = 32; o >= 1; o >>= 1) {
                float ov = __shfl_xor(bv, o, 64);
                int   oi = __shfl_xor(bi, o, 64);
                if (ov > bv || (ov == bv && oi < bi)) { bv = ov; bi = oi; }
            }
            wvals[j] = bv; widx[j] = bi; tsum += bv;
            if (lane == bi) pv = -1.0f;
        }
        if (lane < 8) {
            float myw = wvals[0]; int myi = widx[0];
#pragma unroll
            for (int j = 1; j < 8; ++j) if (lane == j) { myw = wvals[j]; myi = widx[j]; }
            out[(size_t)tg_ * 8 + lane] = myw / tsum;                       // output 0
            out[(size_t)NTOK * 8 + (size_t)tg_ * 8 + lane] = (float)myi;    // output 1
        }
    }
}

extern "C" void kernel_launch(void* const* d_in, const int* in_sizes, int n_in,
                              void* d_out, int out_size, void* d_ws, size_t ws_size,
                              hipStream_t stream) {
    const float* x     = (const float*)d_in[0];
    const float* noise = (const float*)d_in[1];
    const float* Wr    = (const float*)d_in[2];
    const float* br    = (const float*)d_in[3];
    const float* Wn    = (const float*)d_in[4];
    const float* bn    = (const float*)d_in[5];
    float* out = (float*)d_out;
    hipLaunchKernelGGL(router_fused, dim3(NTOK / MT), dim3(512), 0, stream,
                       x, noise, Wr, br, Wn, bn, out);
}